// Round 6
// baseline (67.174 us; speedup 1.0000x reference)
//
#include <hip/hip_runtime.h>

typedef float v2f __attribute__((ext_vector_type(2)));

constexpr int WIDTH  = 96;
constexpr int HEIGHT = 72;
constexpr int NPTS   = WIDTH * HEIGHT;   // 6912
constexpr int BLOCK  = 128;              // threads per block (2 waves)
constexpr int NTILE  = 256;              // n-points per block (2 per thread)
constexpr int MTILE  = 32;               // m-points per block chunk
constexpr int NTB    = NPTS / NTILE;     // 27
constexpr int MTB    = NPTS / MTILE;     // 216
constexpr int NBLK   = NTB * MTB;        // 5832
constexpr int ROWD   = 36;               // floats per duplicated row (144 B)

// exp(-0.1*d) = exp2(d * KEXP)
constexpr float KEXP  = -0.14426950408889634f;  // -0.1 * log2(e)
constexpr float M2K   = -2.0f * KEXP;           // scale for a-side geometry

// Per-point record (logical 18 values, stored DUPLICATED: [v0,v0,v1,v1,...]):
//  0..2  xyz1         3  K*|xyz1|^2
//  4..6  xyz2_t       7  K*|xyz2_t|^2
//  8..10 xyz2_gt     11  K*|xyz2_gt|^2
// 12..14 f1          15..17 f2
__global__ __launch_bounds__(256) void precompute_kernel(
    const float* __restrict__ depth1, const float* __restrict__ depth2,
    const float* __restrict__ pose,   const float* __restrict__ img1,
    const float* __restrict__ img2,   const float* __restrict__ poseg,
    float* __restrict__ Qd)
{
    const int idx = blockIdx.x * 256 + threadIdx.x;

    float R[12], G[12];
#pragma unroll
    for (int i = 0; i < 12; ++i) { R[i] = pose[i]; G[i] = poseg[i]; }

    const int u = idx % WIDTH;
    const int v = idx / WIDTH;
    const float gy = (float)u * (1.0f / 48.0f) - 1.0f;
    const float gz = (float)v * (1.0f / 36.0f) - 1.0f;
    const float d1 = depth1[idx];
    const float d2 = depth2[idx];
    const float x1 = d1, y1 = d1 * gy, z1 = d1 * gz;
    const float x2 = d2, y2 = d2 * gy, z2 = d2 * gz;
    const float xt = R[0] * x2 + R[1] * y2 + R[2]  * z2 + R[3];
    const float yt = R[4] * x2 + R[5] * y2 + R[6]  * z2 + R[7];
    const float zt = R[8] * x2 + R[9] * y2 + R[10] * z2 + R[11];
    const float xg = G[0] * x2 + G[1] * y2 + G[2]  * z2 + G[3];
    const float yg = G[4] * x2 + G[5] * y2 + G[6]  * z2 + G[7];
    const float zg = G[8] * x2 + G[9] * y2 + G[10] * z2 + G[11];

    float o[18];
    o[0] = x1; o[1] = y1; o[2]  = z1; o[3]  = KEXP * (x1*x1 + y1*y1 + z1*z1);
    o[4] = xt; o[5] = yt; o[6]  = zt; o[7]  = KEXP * (xt*xt + yt*yt + zt*zt);
    o[8] = xg; o[9] = yg; o[10] = zg; o[11] = KEXP * (xg*xg + yg*yg + zg*zg);
    o[12] = img1[idx];
    o[13] = img1[NPTS + idx];
    o[14] = img1[2 * NPTS + idx];
    o[15] = img2[idx];
    o[16] = img2[NPTS + idx];
    o[17] = img2[2 * NPTS + idx];

    float4* row = (float4*)(Qd + (size_t)idx * ROWD);
#pragma unroll
    for (int j = 0; j < 9; ++j)
        row[j] = make_float4(o[2 * j], o[2 * j], o[2 * j + 1], o[2 * j + 1]);
}

__global__ __launch_bounds__(BLOCK) void pair_kernel(
    const float* __restrict__ Qd, float* __restrict__ partials)
{
    __shared__ float red[2][5];

    const int t  = threadIdx.x;
    const int bn = blockIdx.x % NTB;
    const int bm = blockIdx.x / NTB;

    // two n-points per thread, packed as v2f; a-side geometry pre-scaled by -2K
    v2f A[18];
    {
        const int n0 = bn * NTILE + t;
        const float4* r0 = (const float4*)(Qd + (size_t)n0 * ROWD);
        const float4* r1 = (const float4*)(Qd + (size_t)(n0 + BLOCK) * ROWD);
#pragma unroll
        for (int j = 0; j < 9; ++j) {
            const float4 w0 = r0[j];
            const float4 w1 = r1[j];
            A[2 * j].x     = w0.x; A[2 * j].y     = w1.x;
            A[2 * j + 1].x = w0.z; A[2 * j + 1].y = w1.z;
        }
#pragma unroll
        for (int grp = 0; grp < 3; ++grp) {
#pragma unroll
            for (int k = 0; k < 3; ++k) A[grp * 4 + k] *= M2K;
        }
    }

    v2f s0 = {0.f, 0.f}, s1 = s0, s2 = s0, s3 = s0, s4 = s0;

    // b-values as wave-uniform <2 x float> loads of duplicated data:
    // scalarized to even-aligned SGPR pairs -> direct v_pk_* sources, no movs.
#define B2(k) (*(const v2f*)(qrow + 2 * (k)))
#define COMPUTE()                                                          \
    do {                                                                   \
        v2f t11 = A[3] + B2(3);                                            \
        t11 = A[0] * B2(0) + t11;                                          \
        t11 = A[1] * B2(1) + t11;                                          \
        t11 = A[2] * B2(2) + t11;                                          \
        v2f t22 = A[7] + B2(7);                                            \
        t22 = A[4] * B2(4) + t22;                                          \
        t22 = A[5] * B2(5) + t22;                                          \
        t22 = A[6] * B2(6) + t22;                                          \
        v2f t12 = A[3] + B2(7);                                            \
        t12 = A[0] * B2(4) + t12;                                          \
        t12 = A[1] * B2(5) + t12;                                          \
        t12 = A[2] * B2(6) + t12;                                          \
        v2f tgg = A[11] + B2(11);                                          \
        tgg = A[8]  * B2(8)  + tgg;                                        \
        tgg = A[9]  * B2(9)  + tgg;                                        \
        tgg = A[10] * B2(10) + tgg;                                        \
        v2f t1g = A[3] + B2(11);                                           \
        t1g = A[0] * B2(8)  + t1g;                                         \
        t1g = A[1] * B2(9)  + t1g;                                         \
        t1g = A[2] * B2(10) + t1g;                                         \
        v2f g11 = A[12] * B2(12);                                          \
        g11 = A[13] * B2(13) + g11;                                        \
        g11 = A[14] * B2(14) + g11;                                        \
        v2f g22 = A[15] * B2(15);                                          \
        g22 = A[16] * B2(16) + g22;                                        \
        g22 = A[17] * B2(17) + g22;                                        \
        v2f g12 = A[12] * B2(15);                                          \
        g12 = A[13] * B2(16) + g12;                                        \
        g12 = A[14] * B2(17) + g12;                                        \
        v2f e11, e22, e12, egg, e1g;                                       \
        e11.x = __builtin_amdgcn_exp2f(t11.x);                             \
        e11.y = __builtin_amdgcn_exp2f(t11.y);                             \
        e22.x = __builtin_amdgcn_exp2f(t22.x);                             \
        e22.y = __builtin_amdgcn_exp2f(t22.y);                             \
        e12.x = __builtin_amdgcn_exp2f(t12.x);                             \
        e12.y = __builtin_amdgcn_exp2f(t12.y);                             \
        egg.x = __builtin_amdgcn_exp2f(tgg.x);                             \
        egg.y = __builtin_amdgcn_exp2f(tgg.y);                             \
        e1g.x = __builtin_amdgcn_exp2f(t1g.x);                             \
        e1g.y = __builtin_amdgcn_exp2f(t1g.y);                             \
        s0 = e11 * g11 + s0;                                               \
        s1 = e22 * g22 + s1;                                               \
        s2 = e12 * g12 + s2;                                               \
        s3 = egg * g22 + s3;                                               \
        s4 = e1g * g12 + s4;                                               \
    } while (0)

    const float* __restrict__ q0 = Qd + (size_t)(bm * MTILE) * ROWD;
#pragma unroll 2
    for (int m = 0; m < MTILE; ++m) {
        const float* __restrict__ qrow = q0 + m * ROWD;
        COMPUTE();
    }
#undef COMPUTE
#undef B2

    // per-thread fold then 64-lane reduction
    float r0 = s0.x + s0.y, r1 = s1.x + s1.y, r2 = s2.x + s2.y,
          r3 = s3.x + s3.y, r4 = s4.x + s4.y;
#pragma unroll
    for (int off = 32; off > 0; off >>= 1) {
        r0 += __shfl_down(r0, off);
        r1 += __shfl_down(r1, off);
        r2 += __shfl_down(r2, off);
        r3 += __shfl_down(r3, off);
        r4 += __shfl_down(r4, off);
    }
    const int wave = t >> 6, lane = t & 63;
    if (lane == 0) {
        red[wave][0] = r0; red[wave][1] = r1; red[wave][2] = r2;
        red[wave][3] = r3; red[wave][4] = r4;
    }
    __syncthreads();
    if (t == 0) {
        partials[0 * NBLK + blockIdx.x] = red[0][0] + red[1][0];
        partials[1 * NBLK + blockIdx.x] = red[0][1] + red[1][1];
        partials[2 * NBLK + blockIdx.x] = red[0][2] + red[1][2];
        partials[3 * NBLK + blockIdx.x] = red[0][3] + red[1][3];
        partials[4 * NBLK + blockIdx.x] = red[0][4] + red[1][4];
    }
}

__global__ __launch_bounds__(256) void finalize_kernel(
    const float* __restrict__ partials, float* __restrict__ out)
{
    __shared__ double red[4][5];
    double l0 = 0, l1 = 0, l2 = 0, l3 = 0, l4 = 0;
    for (int b = threadIdx.x; b < NBLK; b += 256) {
        l0 += partials[0 * NBLK + b];
        l1 += partials[1 * NBLK + b];
        l2 += partials[2 * NBLK + b];
        l3 += partials[3 * NBLK + b];
        l4 += partials[4 * NBLK + b];
    }
#pragma unroll
    for (int off = 32; off > 0; off >>= 1) {
        l0 += __shfl_down(l0, off);
        l1 += __shfl_down(l1, off);
        l2 += __shfl_down(l2, off);
        l3 += __shfl_down(l3, off);
        l4 += __shfl_down(l4, off);
    }
    const int wave = threadIdx.x >> 6, lane = threadIdx.x & 63;
    if (lane == 0) {
        red[wave][0] = l0; red[wave][1] = l1; red[wave][2] = l2;
        red[wave][3] = l3; red[wave][4] = l4;
    }
    __syncthreads();
    if (threadIdx.x == 0) {
        const double a0 = red[0][0] + red[1][0] + red[2][0] + red[3][0];
        const double a1 = red[0][1] + red[1][1] + red[2][1] + red[3][1];
        const double a2 = red[0][2] + red[1][2] + red[2][2] + red[3][2];
        const double a3 = red[0][3] + red[1][3] + red[2][3] + red[3][3];
        const double a4 = red[0][4] + red[1][4] + red[2][4] + red[3][4];
        const double num = a0 + a1 - 2.0 * a2;
        const double den = a0 + a3 - 2.0 * a4;
        out[0] = (float)(num / den);
    }
}

extern "C" void kernel_launch(void* const* d_in, const int* in_sizes, int n_in,
                              void* d_out, int out_size, void* d_ws, size_t ws_size,
                              hipStream_t stream)
{
    const float* depth1 = (const float*)d_in[0];
    const float* depth2 = (const float*)d_in[1];
    const float* pose   = (const float*)d_in[2];
    const float* img1   = (const float*)d_in[3];
    const float* img2   = (const float*)d_in[4];
    const float* poseg  = (const float*)d_in[5];

    float* Qd       = (float*)d_ws;                 // 6912*36 floats = 995 KB
    float* partials = Qd + (size_t)NPTS * ROWD;     // 5*5832 floats  = 117 KB

    precompute_kernel<<<NPTS / 256, 256, 0, stream>>>(depth1, depth2, pose,
                                                      img1, img2, poseg, Qd);
    pair_kernel<<<NBLK, BLOCK, 0, stream>>>(Qd, partials);
    finalize_kernel<<<1, 256, 0, stream>>>(partials, (float*)d_out);
}

// Round 7
// 67.113 us; speedup vs baseline: 1.0009x; 1.0009x over previous
//
#include <hip/hip_runtime.h>

typedef float v2f __attribute__((ext_vector_type(2)));

constexpr int WIDTH  = 96;
constexpr int HEIGHT = 72;
constexpr int NPTS   = WIDTH * HEIGHT;   // 6912
constexpr int BLOCK  = 128;              // threads per block (2 waves)
constexpr int NTILE  = 256;              // n-points per block (2 per thread)
constexpr int MTILE  = 32;               // m-points per block chunk
constexpr int NTB    = NPTS / NTILE;     // 27
constexpr int MTB    = NPTS / MTILE;     // 216
constexpr int NBLK   = NTB * MTB;        // 5832
constexpr int ROWD   = 36;               // floats per duplicated row (144 B)

// exp(-0.1*d) = exp2(d * KEXP)
constexpr float KEXP  = -0.14426950408889634f;  // -0.1 * log2(e)
constexpr float M2K   = -2.0f * KEXP;           // scale for a-side geometry

// ---- forced VOP3P packed f32 ops (compiler won't select these itself) ----
__device__ __forceinline__ v2f pk_add_s(v2f a, v2f b) {            // a + b(sgpr)
    v2f d; asm("v_pk_add_f32 %0, %1, %2" : "=v"(d) : "v"(a), "s"(b)); return d;
}
__device__ __forceinline__ v2f pk_mul_s(v2f a, v2f b) {            // a * b(sgpr)
    v2f d; asm("v_pk_mul_f32 %0, %1, %2" : "=v"(d) : "v"(a), "s"(b)); return d;
}
__device__ __forceinline__ void pk_fma_acc_s(v2f& acc, v2f a, v2f b) { // acc += a*b(sgpr)
    asm("v_pk_fma_f32 %0, %1, %2, %0" : "+v"(acc) : "v"(a), "s"(b));
}
__device__ __forceinline__ void pk_fma_acc(v2f& acc, v2f a, v2f b) {   // acc += a*b
    asm("v_pk_fma_f32 %0, %1, %2, %0" : "+v"(acc) : "v"(a), "v"(b));
}

// Per-point record (logical 18 values, stored DUPLICATED: [v0,v0,v1,v1,...]):
//  0..2  xyz1         3  K*|xyz1|^2
//  4..6  xyz2_t       7  K*|xyz2_t|^2
//  8..10 xyz2_gt     11  K*|xyz2_gt|^2
// 12..14 f1          15..17 f2
__global__ __launch_bounds__(256) void precompute_kernel(
    const float* __restrict__ depth1, const float* __restrict__ depth2,
    const float* __restrict__ pose,   const float* __restrict__ img1,
    const float* __restrict__ img2,   const float* __restrict__ poseg,
    float* __restrict__ Qd)
{
    const int idx = blockIdx.x * 256 + threadIdx.x;

    float R[12], G[12];
#pragma unroll
    for (int i = 0; i < 12; ++i) { R[i] = pose[i]; G[i] = poseg[i]; }

    const int u = idx % WIDTH;
    const int v = idx / WIDTH;
    const float gy = (float)u * (1.0f / 48.0f) - 1.0f;
    const float gz = (float)v * (1.0f / 36.0f) - 1.0f;
    const float d1 = depth1[idx];
    const float d2 = depth2[idx];
    const float x1 = d1, y1 = d1 * gy, z1 = d1 * gz;
    const float x2 = d2, y2 = d2 * gy, z2 = d2 * gz;
    const float xt = R[0] * x2 + R[1] * y2 + R[2]  * z2 + R[3];
    const float yt = R[4] * x2 + R[5] * y2 + R[6]  * z2 + R[7];
    const float zt = R[8] * x2 + R[9] * y2 + R[10] * z2 + R[11];
    const float xg = G[0] * x2 + G[1] * y2 + G[2]  * z2 + G[3];
    const float yg = G[4] * x2 + G[5] * y2 + G[6]  * z2 + G[7];
    const float zg = G[8] * x2 + G[9] * y2 + G[10] * z2 + G[11];

    float o[18];
    o[0] = x1; o[1] = y1; o[2]  = z1; o[3]  = KEXP * (x1*x1 + y1*y1 + z1*z1);
    o[4] = xt; o[5] = yt; o[6]  = zt; o[7]  = KEXP * (xt*xt + yt*yt + zt*zt);
    o[8] = xg; o[9] = yg; o[10] = zg; o[11] = KEXP * (xg*xg + yg*yg + zg*zg);
    o[12] = img1[idx];
    o[13] = img1[NPTS + idx];
    o[14] = img1[2 * NPTS + idx];
    o[15] = img2[idx];
    o[16] = img2[NPTS + idx];
    o[17] = img2[2 * NPTS + idx];

    float4* row = (float4*)(Qd + (size_t)idx * ROWD);
#pragma unroll
    for (int j = 0; j < 9; ++j)
        row[j] = make_float4(o[2 * j], o[2 * j], o[2 * j + 1], o[2 * j + 1]);
}

__global__ __launch_bounds__(BLOCK) void pair_kernel(
    const float* __restrict__ Qd, float* __restrict__ partials)
{
    __shared__ float red[2][5];

    const int t  = threadIdx.x;
    const int bn = blockIdx.x % NTB;
    const int bm = blockIdx.x / NTB;

    // two n-points per thread, packed as v2f; a-side geometry pre-scaled by -2K
    v2f A[18];
    {
        const int n0 = bn * NTILE + t;
        const float4* r0 = (const float4*)(Qd + (size_t)n0 * ROWD);
        const float4* r1 = (const float4*)(Qd + (size_t)(n0 + BLOCK) * ROWD);
#pragma unroll
        for (int j = 0; j < 9; ++j) {
            const float4 w0 = r0[j];
            const float4 w1 = r1[j];
            A[2 * j].x     = w0.x; A[2 * j].y     = w1.x;
            A[2 * j + 1].x = w0.z; A[2 * j + 1].y = w1.z;
        }
#pragma unroll
        for (int grp = 0; grp < 3; ++grp) {
#pragma unroll
            for (int k = 0; k < 3; ++k) A[grp * 4 + k] *= M2K;
        }
    }

    v2f s0 = {0.f, 0.f}, s1 = s0, s2 = s0, s3 = s0, s4 = s0;

    const float* __restrict__ q0 = Qd + (size_t)(bm * MTILE) * ROWD;

#pragma unroll 2
    for (int m = 0; m < MTILE; ++m) {
        const float* __restrict__ qrow = q0 + m * ROWD;
        // wave-uniform duplicated pairs -> SGPR pairs (s_load path)
        v2f bv[18];
#pragma unroll
        for (int k = 0; k < 18; ++k) bv[k] = *(const v2f*)(qrow + 2 * k);

        // distance args (pk ops, b-side in SGPRs)
        v2f t11 = pk_add_s(A[3], bv[3]);
        pk_fma_acc_s(t11, A[0], bv[0]);
        pk_fma_acc_s(t11, A[1], bv[1]);
        pk_fma_acc_s(t11, A[2], bv[2]);

        v2f t22 = pk_add_s(A[7], bv[7]);
        pk_fma_acc_s(t22, A[4], bv[4]);
        pk_fma_acc_s(t22, A[5], bv[5]);
        pk_fma_acc_s(t22, A[6], bv[6]);

        v2f t12 = pk_add_s(A[3], bv[7]);
        pk_fma_acc_s(t12, A[0], bv[4]);
        pk_fma_acc_s(t12, A[1], bv[5]);
        pk_fma_acc_s(t12, A[2], bv[6]);

        v2f tgg = pk_add_s(A[11], bv[11]);
        pk_fma_acc_s(tgg, A[8],  bv[8]);
        pk_fma_acc_s(tgg, A[9],  bv[9]);
        pk_fma_acc_s(tgg, A[10], bv[10]);

        v2f t1g = pk_add_s(A[3], bv[11]);
        pk_fma_acc_s(t1g, A[0], bv[8]);
        pk_fma_acc_s(t1g, A[1], bv[9]);
        pk_fma_acc_s(t1g, A[2], bv[10]);

        // feature grams
        v2f g11 = pk_mul_s(A[12], bv[12]);
        pk_fma_acc_s(g11, A[13], bv[13]);
        pk_fma_acc_s(g11, A[14], bv[14]);

        v2f g22 = pk_mul_s(A[15], bv[15]);
        pk_fma_acc_s(g22, A[16], bv[16]);
        pk_fma_acc_s(g22, A[17], bv[17]);

        v2f g12 = pk_mul_s(A[12], bv[15]);
        pk_fma_acc_s(g12, A[13], bv[16]);
        pk_fma_acc_s(g12, A[14], bv[17]);

        v2f e11, e22, e12, egg, e1g;
        e11.x = __builtin_amdgcn_exp2f(t11.x); e11.y = __builtin_amdgcn_exp2f(t11.y);
        e22.x = __builtin_amdgcn_exp2f(t22.x); e22.y = __builtin_amdgcn_exp2f(t22.y);
        e12.x = __builtin_amdgcn_exp2f(t12.x); e12.y = __builtin_amdgcn_exp2f(t12.y);
        egg.x = __builtin_amdgcn_exp2f(tgg.x); egg.y = __builtin_amdgcn_exp2f(tgg.y);
        e1g.x = __builtin_amdgcn_exp2f(t1g.x); e1g.y = __builtin_amdgcn_exp2f(t1g.y);

        pk_fma_acc(s0, e11, g11);
        pk_fma_acc(s1, e22, g22);
        pk_fma_acc(s2, e12, g12);
        pk_fma_acc(s3, egg, g22);
        pk_fma_acc(s4, e1g, g12);
    }

    // per-thread fold then 64-lane reduction
    float r0 = s0.x + s0.y, r1 = s1.x + s1.y, r2 = s2.x + s2.y,
          r3 = s3.x + s3.y, r4 = s4.x + s4.y;
#pragma unroll
    for (int off = 32; off > 0; off >>= 1) {
        r0 += __shfl_down(r0, off);
        r1 += __shfl_down(r1, off);
        r2 += __shfl_down(r2, off);
        r3 += __shfl_down(r3, off);
        r4 += __shfl_down(r4, off);
    }
    const int wave = t >> 6, lane = t & 63;
    if (lane == 0) {
        red[wave][0] = r0; red[wave][1] = r1; red[wave][2] = r2;
        red[wave][3] = r3; red[wave][4] = r4;
    }
    __syncthreads();
    if (t == 0) {
        partials[0 * NBLK + blockIdx.x] = red[0][0] + red[1][0];
        partials[1 * NBLK + blockIdx.x] = red[0][1] + red[1][1];
        partials[2 * NBLK + blockIdx.x] = red[0][2] + red[1][2];
        partials[3 * NBLK + blockIdx.x] = red[0][3] + red[1][3];
        partials[4 * NBLK + blockIdx.x] = red[0][4] + red[1][4];
    }
}

__global__ __launch_bounds__(256) void finalize_kernel(
    const float* __restrict__ partials, float* __restrict__ out)
{
    __shared__ double red[4][5];
    double l0 = 0, l1 = 0, l2 = 0, l3 = 0, l4 = 0;
    for (int b = threadIdx.x; b < NBLK; b += 256) {
        l0 += partials[0 * NBLK + b];
        l1 += partials[1 * NBLK + b];
        l2 += partials[2 * NBLK + b];
        l3 += partials[3 * NBLK + b];
        l4 += partials[4 * NBLK + b];
    }
#pragma unroll
    for (int off = 32; off > 0; off >>= 1) {
        l0 += __shfl_down(l0, off);
        l1 += __shfl_down(l1, off);
        l2 += __shfl_down(l2, off);
        l3 += __shfl_down(l3, off);
        l4 += __shfl_down(l4, off);
    }
    const int wave = threadIdx.x >> 6, lane = threadIdx.x & 63;
    if (lane == 0) {
        red[wave][0] = l0; red[wave][1] = l1; red[wave][2] = l2;
        red[wave][3] = l3; red[wave][4] = l4;
    }
    __syncthreads();
    if (threadIdx.x == 0) {
        const double a0 = red[0][0] + red[1][0] + red[2][0] + red[3][0];
        const double a1 = red[0][1] + red[1][1] + red[2][1] + red[3][1];
        const double a2 = red[0][2] + red[1][2] + red[2][2] + red[3][2];
        const double a3 = red[0][3] + red[1][3] + red[2][3] + red[3][3];
        const double a4 = red[0][4] + red[1][4] + red[2][4] + red[3][4];
        const double num = a0 + a1 - 2.0 * a2;
        const double den = a0 + a3 - 2.0 * a4;
        out[0] = (float)(num / den);
    }
}

extern "C" void kernel_launch(void* const* d_in, const int* in_sizes, int n_in,
                              void* d_out, int out_size, void* d_ws, size_t ws_size,
                              hipStream_t stream)
{
    const float* depth1 = (const float*)d_in[0];
    const float* depth2 = (const float*)d_in[1];
    const float* pose   = (const float*)d_in[2];
    const float* img1   = (const float*)d_in[3];
    const float* img2   = (const float*)d_in[4];
    const float* poseg  = (const float*)d_in[5];

    float* Qd       = (float*)d_ws;                 // 6912*36 floats = 995 KB
    float* partials = Qd + (size_t)NPTS * ROWD;     // 5*5832 floats  = 117 KB

    precompute_kernel<<<NPTS / 256, 256, 0, stream>>>(depth1, depth2, pose,
                                                      img1, img2, poseg, Qd);
    pair_kernel<<<NBLK, BLOCK, 0, stream>>>(Qd, partials);
    finalize_kernel<<<1, 256, 0, stream>>>(partials, (float*)d_out);
}

// Round 8
// 58.163 us; speedup vs baseline: 1.1549x; 1.1539x over previous
//
#include <hip/hip_runtime.h>

typedef float v2f __attribute__((ext_vector_type(2)));

constexpr int WIDTH  = 96;
constexpr int HEIGHT = 72;
constexpr int NPTS   = WIDTH * HEIGHT;   // 6912

// ---- full (asymmetric) phase: terms s2 (f1_f2), s4 (f1_f2_gt) ----
constexpr int BLOCK  = 128;
constexpr int NTILE  = 256;              // n-points per block (2/thread, v2f)
constexpr int MTILE  = 64;               // m-points per block
constexpr int NTB    = NPTS / NTILE;     // 27
constexpr int MTB    = NPTS / MTILE;     // 108
constexpr int NBF    = NTB * MTB;        // 2916 full blocks

// ---- triangle (symmetric) phase: terms s0 (f1_f1), s1 (f2_f2), s3 (f2_f2_gt) ----
constexpr int TT     = 128;              // square tile edge
constexpr int T      = NPTS / TT;        // 54
constexpr int NBT    = T * (T + 1) / 2;  // 1485 triangle blocks

constexpr int NBLK   = NBT + NBF;        // 4401 total

constexpr int ROWT   = 20;               // triangle table row (80 B)
constexpr int ROWFN  = 8;                // full n-side row (32 B)
constexpr int ROWFM  = 12;               // full m-side row (48 B)

// exp(-0.1*d) = exp2(d * KEXP)
constexpr float KEXP  = -0.14426950408889634f;  // -0.1 * log2(e)
constexpr float M2K   = -2.0f * KEXP;

// QT row (triangle, both sides):
//  0..2 xyz1   3 K|xyz1|^2 | 4..6 xyz2_t  7 K|xyz2_t|^2
//  8..10 xyz2_gt 11 K|..|^2 | 12..14 f1   15..17 f2   18..19 pad
// QFn row (full n-side): 0..2 M2K*xyz1, 3 K|xyz1|^2, 4..6 f1, 7 pad
// QFm row (full m-side): 0..2 xyz2_t, 3 K|..|^2, 4..6 xyz2_gt, 7 K|..|^2,
//                        8..10 f2, 11 pad
__global__ __launch_bounds__(256) void precompute_kernel(
    const float* __restrict__ depth1, const float* __restrict__ depth2,
    const float* __restrict__ pose,   const float* __restrict__ img1,
    const float* __restrict__ img2,   const float* __restrict__ poseg,
    float* __restrict__ QT, float* __restrict__ QFn, float* __restrict__ QFm)
{
    const int idx = blockIdx.x * 256 + threadIdx.x;

    float R[12], G[12];
#pragma unroll
    for (int i = 0; i < 12; ++i) { R[i] = pose[i]; G[i] = poseg[i]; }

    const int u = idx % WIDTH;
    const int v = idx / WIDTH;
    const float gy = (float)u * (1.0f / 48.0f) - 1.0f;
    const float gz = (float)v * (1.0f / 36.0f) - 1.0f;
    const float d1 = depth1[idx];
    const float d2 = depth2[idx];
    const float x1 = d1, y1 = d1 * gy, z1 = d1 * gz;
    const float x2 = d2, y2 = d2 * gy, z2 = d2 * gz;
    const float xt = R[0] * x2 + R[1] * y2 + R[2]  * z2 + R[3];
    const float yt = R[4] * x2 + R[5] * y2 + R[6]  * z2 + R[7];
    const float zt = R[8] * x2 + R[9] * y2 + R[10] * z2 + R[11];
    const float xg = G[0] * x2 + G[1] * y2 + G[2]  * z2 + G[3];
    const float yg = G[4] * x2 + G[5] * y2 + G[6]  * z2 + G[7];
    const float zg = G[8] * x2 + G[9] * y2 + G[10] * z2 + G[11];

    const float q1 = KEXP * (x1*x1 + y1*y1 + z1*z1);
    const float qt = KEXP * (xt*xt + yt*yt + zt*zt);
    const float qg = KEXP * (xg*xg + yg*yg + zg*zg);
    const float f1a = img1[idx], f1b = img1[NPTS + idx], f1c = img1[2*NPTS + idx];
    const float f2a = img2[idx], f2b = img2[NPTS + idx], f2c = img2[2*NPTS + idx];

    float4* qt_row = (float4*)(QT + (size_t)idx * ROWT);
    qt_row[0] = make_float4(x1, y1, z1, q1);
    qt_row[1] = make_float4(xt, yt, zt, qt);
    qt_row[2] = make_float4(xg, yg, zg, qg);
    qt_row[3] = make_float4(f1a, f1b, f1c, f2a);
    qt_row[4] = make_float4(f2b, f2c, 0.f, 0.f);

    float4* fn_row = (float4*)(QFn + (size_t)idx * ROWFN);
    fn_row[0] = make_float4(M2K * x1, M2K * y1, M2K * z1, q1);
    fn_row[1] = make_float4(f1a, f1b, f1c, 0.f);

    float4* fm_row = (float4*)(QFm + (size_t)idx * ROWFM);
    fm_row[0] = make_float4(xt, yt, zt, qt);
    fm_row[1] = make_float4(xg, yg, zg, qg);
    fm_row[2] = make_float4(f2a, f2b, f2c, 0.f);
}

__global__ __launch_bounds__(BLOCK) void pair_kernel(
    const float* __restrict__ QT,  const float* __restrict__ QFn,
    const float* __restrict__ QFm,
    float* __restrict__ pT, float* __restrict__ pF)
{
    __shared__ float red[2][3];
    const int t = threadIdx.x;

    if (blockIdx.x < NBT) {
        // ---------------- triangle phase: s0, s1, s3 ----------------
        int rem = blockIdx.x, i = 0;
        while (rem >= T - i) { rem -= T - i; ++i; }   // uniform, <=54 iters
        const int j = i + rem;

        // n-point (1/thread) from QT; prescale dot operands by -2K
        float A[18];
        {
            const float4* r = (const float4*)(QT + (size_t)(i * TT + t) * ROWT);
            const float4 w0 = r[0], w1 = r[1], w2 = r[2], w3 = r[3], w4 = r[4];
            A[0]=M2K*w0.x; A[1]=M2K*w0.y; A[2]=M2K*w0.z; A[3]=w0.w;
            A[4]=M2K*w1.x; A[5]=M2K*w1.y; A[6]=M2K*w1.z; A[7]=w1.w;
            A[8]=M2K*w2.x; A[9]=M2K*w2.y; A[10]=M2K*w2.z; A[11]=w2.w;
            A[12]=w3.x; A[13]=w3.y; A[14]=w3.z;
            A[15]=w3.w; A[16]=w4.x; A[17]=w4.y;
        }

        float s0 = 0.f, s1 = 0.f, s3 = 0.f;
        const float* __restrict__ q0 = QT + (size_t)(j * TT) * ROWT;
#pragma unroll 2
        for (int m = 0; m < TT; ++m) {
            const float* __restrict__ b = q0 + m * ROWT;   // wave-uniform
            float t11 = A[3] + b[3];
            t11 = A[0] * b[0] + t11;
            t11 = A[1] * b[1] + t11;
            t11 = A[2] * b[2] + t11;
            float t22 = A[7] + b[7];
            t22 = A[4] * b[4] + t22;
            t22 = A[5] * b[5] + t22;
            t22 = A[6] * b[6] + t22;
            float tgg = A[11] + b[11];
            tgg = A[8]  * b[8]  + tgg;
            tgg = A[9]  * b[9]  + tgg;
            tgg = A[10] * b[10] + tgg;
            float g11 = A[12] * b[12];
            g11 = A[13] * b[13] + g11;
            g11 = A[14] * b[14] + g11;
            float g22 = A[15] * b[15];
            g22 = A[16] * b[16] + g22;
            g22 = A[17] * b[17] + g22;
            const float e11 = __builtin_amdgcn_exp2f(t11);
            const float e22 = __builtin_amdgcn_exp2f(t22);
            const float egg = __builtin_amdgcn_exp2f(tgg);
            s0 = e11 * g11 + s0;
            s1 = e22 * g22 + s1;
            s3 = egg * g22 + s3;
        }
        const float w = (i == j) ? 1.f : 2.f;
        s0 *= w; s1 *= w; s3 *= w;

#pragma unroll
        for (int off = 32; off > 0; off >>= 1) {
            s0 += __shfl_down(s0, off);
            s1 += __shfl_down(s1, off);
            s3 += __shfl_down(s3, off);
        }
        const int wave = t >> 6, lane = t & 63;
        if (lane == 0) { red[wave][0]=s0; red[wave][1]=s1; red[wave][2]=s3; }
        __syncthreads();
        if (t == 0) {
            pT[0 * NBT + blockIdx.x] = red[0][0] + red[1][0];
            pT[1 * NBT + blockIdx.x] = red[0][1] + red[1][1];
            pT[2 * NBT + blockIdx.x] = red[0][2] + red[1][2];
        }
    } else {
        // ---------------- full phase: s2, s4 ----------------
        const int blk = blockIdx.x - NBT;
        const int bn = blk % NTB;
        const int bm = blk / NTB;

        v2f A[7];   // 0..2 M2K*xyz1, 3 K|xyz1|^2, 4..6 f1  (two n-pts packed)
        {
            const int n0 = bn * NTILE + t;
            const float4* r0 = (const float4*)(QFn + (size_t)n0 * ROWFN);
            const float4* r1 = (const float4*)(QFn + (size_t)(n0 + BLOCK) * ROWFN);
            const float4 a0 = r0[0], a1 = r0[1], c0 = r1[0], c1 = r1[1];
            A[0].x=a0.x; A[0].y=c0.x;  A[1].x=a0.y; A[1].y=c0.y;
            A[2].x=a0.z; A[2].y=c0.z;  A[3].x=a0.w; A[3].y=c0.w;
            A[4].x=a1.x; A[4].y=c1.x;  A[5].x=a1.y; A[5].y=c1.y;
            A[6].x=a1.z; A[6].y=c1.z;
        }

        v2f s2 = {0.f, 0.f}, s4 = s2;
        const float* __restrict__ q0 = QFm + (size_t)(bm * MTILE) * ROWFM;
#pragma unroll 2
        for (int m = 0; m < MTILE; ++m) {
            const float* __restrict__ b = q0 + m * ROWFM;  // wave-uniform
            v2f t12 = A[3] + b[3];
            t12 = A[0] * b[0] + t12;
            t12 = A[1] * b[1] + t12;
            t12 = A[2] * b[2] + t12;
            v2f t1g = A[3] + b[7];
            t1g = A[0] * b[4] + t1g;
            t1g = A[1] * b[5] + t1g;
            t1g = A[2] * b[6] + t1g;
            v2f g12 = A[4] * b[8];
            g12 = A[5] * b[9]  + g12;
            g12 = A[6] * b[10] + g12;
            v2f e12, e1g;
            e12.x = __builtin_amdgcn_exp2f(t12.x);
            e12.y = __builtin_amdgcn_exp2f(t12.y);
            e1g.x = __builtin_amdgcn_exp2f(t1g.x);
            e1g.y = __builtin_amdgcn_exp2f(t1g.y);
            s2 = e12 * g12 + s2;
            s4 = e1g * g12 + s4;
        }

        float r2 = s2.x + s2.y, r4 = s4.x + s4.y;
#pragma unroll
        for (int off = 32; off > 0; off >>= 1) {
            r2 += __shfl_down(r2, off);
            r4 += __shfl_down(r4, off);
        }
        const int wave = t >> 6, lane = t & 63;
        if (lane == 0) { red[wave][0] = r2; red[wave][1] = r4; }
        __syncthreads();
        if (t == 0) {
            pF[0 * NBF + blk] = red[0][0] + red[1][0];
            pF[1 * NBF + blk] = red[0][1] + red[1][1];
        }
    }
}

__global__ __launch_bounds__(256) void finalize_kernel(
    const float* __restrict__ pT, const float* __restrict__ pF,
    float* __restrict__ out)
{
    __shared__ double red[4][5];
    double l0 = 0, l1 = 0, l2 = 0, l3 = 0, l4 = 0;
    for (int b = threadIdx.x; b < NBT; b += 256) {
        l0 += pT[0 * NBT + b];
        l1 += pT[1 * NBT + b];
        l3 += pT[2 * NBT + b];
    }
    for (int b = threadIdx.x; b < NBF; b += 256) {
        l2 += pF[0 * NBF + b];
        l4 += pF[1 * NBF + b];
    }
#pragma unroll
    for (int off = 32; off > 0; off >>= 1) {
        l0 += __shfl_down(l0, off);
        l1 += __shfl_down(l1, off);
        l2 += __shfl_down(l2, off);
        l3 += __shfl_down(l3, off);
        l4 += __shfl_down(l4, off);
    }
    const int wave = threadIdx.x >> 6, lane = threadIdx.x & 63;
    if (lane == 0) {
        red[wave][0] = l0; red[wave][1] = l1; red[wave][2] = l2;
        red[wave][3] = l3; red[wave][4] = l4;
    }
    __syncthreads();
    if (threadIdx.x == 0) {
        const double a0 = red[0][0] + red[1][0] + red[2][0] + red[3][0];
        const double a1 = red[0][1] + red[1][1] + red[2][1] + red[3][1];
        const double a2 = red[0][2] + red[1][2] + red[2][2] + red[3][2];
        const double a3 = red[0][3] + red[1][3] + red[2][3] + red[3][3];
        const double a4 = red[0][4] + red[1][4] + red[2][4] + red[3][4];
        const double num = a0 + a1 - 2.0 * a2;
        const double den = a0 + a3 - 2.0 * a4;
        out[0] = (float)(num / den);
    }
}

extern "C" void kernel_launch(void* const* d_in, const int* in_sizes, int n_in,
                              void* d_out, int out_size, void* d_ws, size_t ws_size,
                              hipStream_t stream)
{
    const float* depth1 = (const float*)d_in[0];
    const float* depth2 = (const float*)d_in[1];
    const float* pose   = (const float*)d_in[2];
    const float* img1   = (const float*)d_in[3];
    const float* img2   = (const float*)d_in[4];
    const float* poseg  = (const float*)d_in[5];

    float* QT  = (float*)d_ws;                       // 6912*20 f = 553 KB
    float* QFn = QT  + (size_t)NPTS * ROWT;          // 6912* 8 f = 221 KB
    float* QFm = QFn + (size_t)NPTS * ROWFN;         // 6912*12 f = 332 KB
    float* pT  = QFm + (size_t)NPTS * ROWFM;         // 3*1485 f
    float* pF  = pT  + 3 * NBT;                      // 2*2916 f

    precompute_kernel<<<NPTS / 256, 256, 0, stream>>>(depth1, depth2, pose,
                                                      img1, img2, poseg,
                                                      QT, QFn, QFm);
    pair_kernel<<<NBLK, BLOCK, 0, stream>>>(QT, QFn, QFm, pT, pF);
    finalize_kernel<<<1, 256, 0, stream>>>(pT, pF, (float*)d_out);
}